// Round 7
// baseline (244.056 us; speedup 1.0000x reference)
//
#include <hip/hip_runtime.h>

#define GN 4096
#define CAP 512
#define NGRAPH 64

// ============ kernel 1: CSR build (blocks 64..4159) ∥ layer-1 GEMM+scores
// (blocks 0..63). GEMM is LDS/VALU-bound, scan is HBM-bound -> they overlap.
// W layout [2][K][32]; col c -> head c>>5, feat c&31. s1:[2][GN], s2i:[GN][2].
__global__ __launch_bounds__(256) void csr_gemm1(
    const float* __restrict__ adj, const float* __restrict__ x,
    const float* __restrict__ W, const float* __restrict__ bias,
    const float* __restrict__ a1w, const float* __restrict__ a1b,
    const float* __restrict__ a2w, const float* __restrict__ a2b,
    int* __restrict__ cnt_, int* __restrict__ col_,
    float* __restrict__ F, float* __restrict__ s1, float* __restrict__ s2i)
{
    __shared__ float As[16][68];
    __shared__ float Bs[16][68];
    __shared__ int lcnt;
    int t = threadIdx.x;
    if (blockIdx.x < 64) {
        // ----- layer-1 GEMM: 64x64 tile, K=512, 4x4 register tiles -----
        int i0 = blockIdx.x * 64;
        int tx = t & 15, ty = t >> 4;
        float acc[4][4] = {};
        for (int kc = 0; kc < 512; kc += 16) {
#pragma unroll
            for (int p = 0; p < 4; ++p) {
                int q = t + p * 256;
                int m = q >> 4, kk = q & 15;
                As[kk][m] = x[(size_t)(i0 + m) * 512 + kc + kk];
            }
            {
                int kk = t >> 4, n0 = (t & 15) * 4;
                const float* wp = W + (size_t)(n0 >> 5) * 512 * 32
                                    + (size_t)(kc + kk) * 32 + (n0 & 31);
                *(float4*)&Bs[kk][n0] = *(const float4*)wp;
            }
            __syncthreads();
#pragma unroll
            for (int kk = 0; kk < 16; ++kk) {
                float4 a4 = *(const float4*)&As[kk][ty * 4];
                float4 b4 = *(const float4*)&Bs[kk][tx * 4];
                float a[4] = {a4.x, a4.y, a4.z, a4.w};
                float b[4] = {b4.x, b4.y, b4.z, b4.w};
#pragma unroll
                for (int i = 0; i < 4; ++i)
#pragma unroll
                    for (int j = 0; j < 4; ++j) acc[i][j] += a[i] * b[j];
            }
            __syncthreads();
        }
        int col0 = tx * 4;
        float4 bi = *(const float4*)&bias[col0];
        float4 w1 = *(const float4*)&a1w[col0];
        float4 w2 = *(const float4*)&a2w[col0];
        int head = tx >> 3;
#pragma unroll
        for (int i = 0; i < 4; ++i) {
            int row = i0 + ty * 4 + i;
            float v0 = acc[i][0] + bi.x;
            float v1 = acc[i][1] + bi.y;
            float v2 = acc[i][2] + bi.z;
            float v3 = acc[i][3] + bi.w;
            float4 v4 = {v0, v1, v2, v3};
            *(float4*)&F[(size_t)row * 64 + col0] = v4;
            float p1 = v0 * w1.x + v1 * w1.y + v2 * w1.z + v3 * w1.w;
            float p2 = v0 * w2.x + v1 * w2.y + v2 * w2.z + v3 * w2.w;
#pragma unroll
            for (int off = 1; off < 8; off <<= 1) {
                p1 += __shfl_xor(p1, off);
                p2 += __shfl_xor(p2, off);
            }
            if ((tx & 7) == 0) {
                s1[head * GN + row] = p1 + a1b[head];
                s2i[row * 2 + head] = p2 + a2b[head];
            }
        }
    } else {
        // ----- CSR build: one row per block, ballot compaction -----
        int i = blockIdx.x - 64;
        int wv = t >> 6, lane = t & 63;
        if (t == 0) lcnt = 0;
        __syncthreads();
        const float* row = adj + (size_t)i * GN;
        int* cols = col_ + (size_t)i * CAP;
        int wbase = wv * 1024;
#pragma unroll
        for (int q = 0; q < 4; ++q) {
            int j = wbase + q * 256 + lane * 4;
            float4 v = *(const float4*)(row + j);
            int mask = (v.x != 0.f ? 1 : 0) | (v.y != 0.f ? 2 : 0)
                     | (v.z != 0.f ? 4 : 0) | (v.w != 0.f ? 8 : 0);
            int pc = __popc(mask);
            int scan = pc;
#pragma unroll
            for (int off = 1; off < 64; off <<= 1) {
                int nn = __shfl_up(scan, off);
                if (lane >= off) scan += nn;
            }
            int total = __shfl(scan, 63);
            int basew = 0;
            if (lane == 63 && total) basew = atomicAdd(&lcnt, total);
            basew = __shfl(basew, 63);
            int p = basew + scan - pc;
            while (mask) {
                int b = __ffs(mask) - 1;
                mask &= mask - 1;
                if (p < CAP) cols[p] = j + b;
                ++p;
            }
        }
        __syncthreads();
        if (t == 0) cnt_[i] = lcnt < CAP ? lcnt : CAP;
    }
}

// ============ attention, optionally fused with next layer's row-local linear
// + scores (f_next[i] = relu_out_row @ Wn + bn, per-head score dots).
template<bool FUSE>
__global__ __launch_bounds__(256) void attn_fused(
    const float* __restrict__ f, const float* __restrict__ s1,
    const float* __restrict__ s2i, const int* __restrict__ cnt_,
    const int* __restrict__ col_, float* __restrict__ xout, int ocol0,
    const float* __restrict__ Wn, const float* __restrict__ bn,
    const float* __restrict__ a1w, const float* __restrict__ a1b,
    const float* __restrict__ a2w, const float* __restrict__ a2b,
    float* __restrict__ fn, float* __restrict__ s1n, float* __restrict__ s2in)
{
    __shared__ float w0[CAP], w1[CAP];
    __shared__ int colsS[CAP];
    __shared__ float red[4][4];
    __shared__ float part[4][64];
    __shared__ float Bs2[FUSE ? 64 : 1][68];
    __shared__ float orow[FUSE ? 64 : 1];
    __shared__ float part2[FUSE ? 4 : 1][64];
    int i = blockIdx.x, t = threadIdx.x;
    int wv = t >> 6, lane = t & 63;
    if (FUSE) {
        // stage Wn: 64 k x 64 cols ([2][64][32] layout)
#pragma unroll
        for (int p = 0; p < 4; ++p) {
            int idx = t + p * 256;
            int kk = idx >> 4, c0 = (idx & 15) * 4;
            *(float4*)&Bs2[kk][c0] =
                *(const float4*)&Wn[(size_t)(c0 >> 5) * 64 * 32
                                    + (size_t)kk * 32 + (c0 & 31)];
        }
    }
    int cnt = cnt_[i];
    const int* cols = col_ + (size_t)i * CAP;
    for (int c = t; c < cnt; c += 256) colsS[c] = cols[c];
    __syncthreads();
    float s10 = s1[i], s11 = s1[GN + i];
    float m0 = -1e30f, m1 = -1e30f;
    for (int c = t; c < cnt; c += 256) {
        int j = colsS[c];
        float2 s2v = *(const float2*)&s2i[j * 2];
        float e0 = s10 + s2v.x; e0 = e0 > 0.f ? e0 : 0.01f * e0;
        float e1 = s11 + s2v.y; e1 = e1 > 0.f ? e1 : 0.01f * e1;
        w0[c] = e0; w1[c] = e1;
        m0 = fmaxf(m0, e0); m1 = fmaxf(m1, e1);
    }
#pragma unroll
    for (int off = 32; off; off >>= 1) {
        m0 = fmaxf(m0, __shfl_xor(m0, off));
        m1 = fmaxf(m1, __shfl_xor(m1, off));
    }
    if (lane == 0) { red[wv][0] = m0; red[wv][1] = m1; }
    __syncthreads();
    m0 = fmaxf(fmaxf(red[0][0], red[1][0]), fmaxf(red[2][0], red[3][0]));
    m1 = fmaxf(fmaxf(red[0][1], red[1][1]), fmaxf(red[2][1], red[3][1]));
    float sum0 = 0.f, sum1 = 0.f;
    for (int c = t; c < cnt; c += 256) {
        float v0 = __expf(w0[c] - m0); w0[c] = v0; sum0 += v0;
        float v1 = __expf(w1[c] - m1); w1[c] = v1; sum1 += v1;
    }
#pragma unroll
    for (int off = 32; off; off >>= 1) {
        sum0 += __shfl_xor(sum0, off);
        sum1 += __shfl_xor(sum1, off);
    }
    if (lane == 0) { red[wv][2] = sum0; red[wv][3] = sum1; }
    __syncthreads();
    sum0 = red[0][2] + red[1][2] + red[2][2] + red[3][2];
    sum1 = red[0][3] + red[1][3] + red[2][3] + red[3][3];
    int head = lane >> 5;
    float o = 0.f;
    for (int c = wv; c < cnt; c += 4) {
        int j = colsS[c];
        float wgt = head ? w1[c] : w0[c];
        o += wgt * f[(size_t)j * 64 + lane];
    }
    part[wv][lane] = o;
    __syncthreads();
    if (wv == 0) {
        o = part[0][lane] + part[1][lane] + part[2][lane] + part[3][lane];
        float denom = head ? sum1 : sum0;
        float v = o / denom;
        v = v > 0.f ? v : 0.f;
        xout[(size_t)i * 192 + ocol0 + lane] = v;
        if (FUSE) orow[lane] = v;
    }
    if (FUSE) {
        __syncthreads();
        // f_next[i][c] = sum_k orow[k] * Bs2[k][c]; k-sliced over 4 waves
        int c = t & 63, ks = t >> 6;
        float acc = 0.f;
#pragma unroll
        for (int k = 0; k < 16; ++k)
            acc += orow[ks * 16 + k] * Bs2[ks * 16 + k][c];
        part2[ks][c] = acc;
        __syncthreads();
        if (wv == 0) {
            float val = part2[0][lane] + part2[1][lane]
                      + part2[2][lane] + part2[3][lane] + bn[lane];
            fn[(size_t)i * 64 + lane] = val;
            float p1 = val * a1w[lane];
            float p2 = val * a2w[lane];
#pragma unroll
            for (int off = 1; off < 32; off <<= 1) {
                p1 += __shfl_xor(p1, off);
                p2 += __shfl_xor(p2, off);
            }
            if ((lane & 31) == 0) {
                int hd = lane >> 5;
                s1n[hd * GN + i] = p1 + a1b[hd];
                s2in[i * 2 + hd] = p2 + a2b[hd];
            }
        }
    }
}

// ============ fused pooling + classifier (batch sorted -> binary search) ====
__global__ __launch_bounds__(192) void pool_classify(
    const float* __restrict__ hbuf, const int* __restrict__ batch,
    const float* __restrict__ Wf, const float* __restrict__ bfb,
    float* __restrict__ out)
{
    __shared__ int bnd[2];
    __shared__ float pooled[192];
    __shared__ float z[10];
    __shared__ float red[2];
    int g = blockIdx.x, t = threadIdx.x;
    if (t == 0) {
        int lo = 0, hi = GN;
        while (lo < hi) { int mid = (lo + hi) >> 1; if (batch[mid] < g) lo = mid + 1; else hi = mid; }
        bnd[0] = lo;
        hi = GN;
        while (lo < hi) { int mid = (lo + hi) >> 1; if (batch[mid] < g + 1) lo = mid + 1; else hi = mid; }
        bnd[1] = lo;
    }
    __syncthreads();
    int s = bnd[0], e = bnd[1];
    float a0 = 0.f, a1 = 0.f, a2 = 0.f, a3 = 0.f;
    int n = s;
    for (; n + 3 < e; n += 4) {
        a0 += hbuf[(size_t)(n + 0) * 192 + t];
        a1 += hbuf[(size_t)(n + 1) * 192 + t];
        a2 += hbuf[(size_t)(n + 2) * 192 + t];
        a3 += hbuf[(size_t)(n + 3) * 192 + t];
    }
    for (; n < e; ++n) a0 += hbuf[(size_t)n * 192 + t];
    float acc = (a0 + a1) + (a2 + a3);
    pooled[t] = (e > s) ? acc / (float)(e - s) : 0.f;
    __syncthreads();
    if (t < 10) {
        float zt = bfb[t];
        for (int c = 0; c < 192; ++c) zt += pooled[c] * Wf[c * 10 + t];
        z[t] = zt;
    }
    __syncthreads();
    if (t == 0) {
        float m = z[0];
        for (int o = 1; o < 10; ++o) m = fmaxf(m, z[o]);
        float ssum = 0.f;
        for (int o = 0; o < 10; ++o) ssum += __expf(z[o] - m);
        red[0] = m; red[1] = ssum;
    }
    __syncthreads();
    if (t < 10) out[g * 10 + t] = __expf(z[t] - red[0]) / red[1];
}

extern "C" void kernel_launch(void* const* d_in, const int* in_sizes, int n_in,
                              void* d_out, int out_size, void* d_ws, size_t ws_size,
                              hipStream_t stream)
{
    const float* x    = (const float*)d_in[0];
    const float* adj  = (const float*)d_in[1];
    const int*   batch= (const int*)d_in[2];
    const float* W1   = (const float*)d_in[3];
    const float* b1   = (const float*)d_in[4];
    const float* a1w1 = (const float*)d_in[5];
    const float* a1b1 = (const float*)d_in[6];
    const float* a2w1 = (const float*)d_in[7];
    const float* a2b1 = (const float*)d_in[8];
    const float* W2   = (const float*)d_in[9];
    const float* b2   = (const float*)d_in[10];
    const float* a1w2 = (const float*)d_in[11];
    const float* a1b2 = (const float*)d_in[12];
    const float* a2w2 = (const float*)d_in[13];
    const float* a2b2 = (const float*)d_in[14];
    const float* W3   = (const float*)d_in[15];
    const float* b3   = (const float*)d_in[16];
    const float* a1w3 = (const float*)d_in[17];
    const float* a1b3 = (const float*)d_in[18];
    const float* a2w3 = (const float*)d_in[19];
    const float* a2b3 = (const float*)d_in[20];
    const float* Wf   = (const float*)d_in[21];
    const float* bf   = (const float*)d_in[22];
    float* out = (float*)d_out;

    char* base = (char*)d_ws;
    int*   csr_cnt = (int*)(base + 0);            // 16 KiB
    float* s1a     = (float*)(base + 16384);      // 32 KiB each
    float* s2a     = (float*)(base + 49152);
    float* s1b     = (float*)(base + 81920);
    float* s2b     = (float*)(base + 114688);
    float* s1c     = (float*)(base + 147456);
    float* s2c     = (float*)(base + 180224);
    float* fbuf1   = (float*)(base + 212992);     // 1 MiB each
    float* fbuf2   = (float*)(base + 1261568);
    float* fbuf3   = (float*)(base + 2310144);
    float* hbuf    = (float*)(base + 3358720);    // 3 MiB
    int*   csr_col = (int*)(base + 6504448);      // 8 MiB
    (void)ws_size; (void)n_in; (void)in_sizes; (void)out_size;

    // 1: CSR scan (HBM-bound) overlapped with layer-1 GEMM+scores (VALU-bound)
    csr_gemm1<<<64 + GN, 256, 0, stream>>>(adj, x, W1, b1, a1w1, a1b1, a2w1, a2b1,
                                           csr_cnt, csr_col, fbuf1, s1a, s2a);
    // 2: attn layer 1 + fused layer-2 linear/scores
    attn_fused<true><<<GN, 256, 0, stream>>>(fbuf1, s1a, s2a, csr_cnt, csr_col,
                                             hbuf, 0, W2, b2, a1w2, a1b2, a2w2, a2b2,
                                             fbuf2, s1b, s2b);
    // 3: attn layer 2 + fused layer-3 linear/scores
    attn_fused<true><<<GN, 256, 0, stream>>>(fbuf2, s1b, s2b, csr_cnt, csr_col,
                                             hbuf, 64, W3, b3, a1w3, a1b3, a2w3, a2b3,
                                             fbuf3, s1c, s2c);
    // 4: attn layer 3 (plain)
    attn_fused<false><<<GN, 256, 0, stream>>>(fbuf3, s1c, s2c, csr_cnt, csr_col,
                                              hbuf, 128, W3, b3, a1w3, a1b3, a2w3, a2b3,
                                              fbuf1, s1a, s2a);
    // 5: pooling + classifier
    pool_classify<<<NGRAPH, 192, 0, stream>>>(hbuf, batch, Wf, bf, out);
}

// Round 8
// 226.430 us; speedup vs baseline: 1.0778x; 1.0778x over previous
//
#include <hip/hip_runtime.h>

#define GN 4096
#define CAP 512
#define NGRAPH 64

// ---------- layer-1 GEMM partials: 64x64 tile, K-split 8 -> 512 blocks ------
// W layout [2][K][32]; col c -> head c>>5, feat c&31. pbuf[ks][row][64].
template<int K, int NSPLIT>
__global__ __launch_bounds__(256) void linear_partial(
    const float* __restrict__ A, int lda, const float* __restrict__ W,
    float* __restrict__ pbuf)
{
    __shared__ float As[16][66];
    __shared__ float Bs[16][68];
    const int KS = K / NSPLIT;
    int tile = blockIdx.x / NSPLIT, ks = blockIdx.x % NSPLIT;
    int i0 = tile * 64;
    int t = threadIdx.x, tx = t & 15, ty = t >> 4;
    float acc[4][4] = {};
    for (int kc = ks * KS; kc < ks * KS + KS; kc += 16) {
        {   // stage A: 64 rows x 16 k, float4 per thread
            int m = t >> 2, k4 = (t & 3) * 4;
            float4 a4 = *(const float4*)&A[(size_t)(i0 + m) * lda + kc + k4];
            As[k4 + 0][m] = a4.x; As[k4 + 1][m] = a4.y;
            As[k4 + 2][m] = a4.z; As[k4 + 3][m] = a4.w;
        }
        {   // stage B: 16 k x 64 cols, float4 per thread
            int kk = t >> 4, c0 = (t & 15) * 4;
            const float* wp = W + (size_t)(c0 >> 5) * K * 32
                                + (size_t)(kc + kk) * 32 + (c0 & 31);
            *(float4*)&Bs[kk][c0] = *(const float4*)wp;
        }
        __syncthreads();
#pragma unroll
        for (int kk = 0; kk < 16; ++kk) {
            float4 a4 = *(const float4*)&As[kk][ty * 4];
            float4 b4 = *(const float4*)&Bs[kk][tx * 4];
            float a[4] = {a4.x, a4.y, a4.z, a4.w};
            float b[4] = {b4.x, b4.y, b4.z, b4.w};
#pragma unroll
            for (int ii = 0; ii < 4; ++ii)
#pragma unroll
                for (int jj = 0; jj < 4; ++jj) acc[ii][jj] += a[ii] * b[jj];
        }
        __syncthreads();
    }
#pragma unroll
    for (int ii = 0; ii < 4; ++ii) {
        int r = i0 + ty * 4 + ii;
        float4 v = {acc[ii][0], acc[ii][1], acc[ii][2], acc[ii][3]};
        *(float4*)&pbuf[((size_t)ks * GN + r) * 64 + tx * 4] = v;
    }
}

// ---------- reduce partials + bias -> f, fused scores -----------------------
// s1 layout [2][GN]; s2i interleaved [GN][2].
template<int NSPLIT>
__global__ __launch_bounds__(256) void reduce_scores(
    const float* __restrict__ pbuf, const float* __restrict__ bias,
    const float* __restrict__ a1w, const float* __restrict__ a1b,
    const float* __restrict__ a2w, const float* __restrict__ a2b,
    float* __restrict__ f, float* __restrict__ s1, float* __restrict__ s2i)
{
    int t = threadIdx.x;
    int r = blockIdx.x * 16 + (t >> 4);
    int c0 = (t & 15) * 4;
    float vx = 0.f, vy = 0.f, vz = 0.f, vw = 0.f;
#pragma unroll
    for (int ks = 0; ks < NSPLIT; ++ks) {
        float4 p = *(const float4*)&pbuf[((size_t)ks * GN + r) * 64 + c0];
        vx += p.x; vy += p.y; vz += p.z; vw += p.w;
    }
    float4 bi = *(const float4*)&bias[c0];
    vx += bi.x; vy += bi.y; vz += bi.z; vw += bi.w;
    float4 v = {vx, vy, vz, vw};
    *(float4*)&f[(size_t)r * 64 + c0] = v;
    float4 w1 = *(const float4*)&a1w[c0];
    float4 w2 = *(const float4*)&a2w[c0];
    float p1 = vx * w1.x + vy * w1.y + vz * w1.z + vw * w1.w;
    float p2 = vx * w2.x + vy * w2.y + vz * w2.z + vw * w2.w;
#pragma unroll
    for (int off = 1; off < 8; off <<= 1) {
        p1 += __shfl_xor(p1, off);
        p2 += __shfl_xor(p2, off);
    }
    if ((t & 7) == 0) {
        int head = (t >> 3) & 1;
        s1[head * GN + r] = p1 + a1b[head];
        s2i[r * 2 + head] = p2 + a2b[head];
    }
}

// ---------- layers 2/3: K=64 linear + fused scores, 16-row tiles ------------
__global__ __launch_bounds__(256) void linear_scores16(
    const float* __restrict__ A, int lda,
    const float* __restrict__ W, const float* __restrict__ bias,
    const float* __restrict__ a1w, const float* __restrict__ a1b,
    const float* __restrict__ a2w, const float* __restrict__ a2b,
    float* __restrict__ F, float* __restrict__ s1, float* __restrict__ s2i)
{
    __shared__ float As[64][18];   // [k][row]
    __shared__ float Bs[64][68];   // [k][col]
    int i0 = blockIdx.x * 16;
    int t = threadIdx.x, tx = t & 15, ty = t >> 4;
    {   // stage A: 16 rows x 64 k, one float4 per thread
        int m = t >> 4, k4 = (t & 15) * 4;
        float4 a4 = *(const float4*)&A[(size_t)(i0 + m) * lda + k4];
        As[k4 + 0][m] = a4.x; As[k4 + 1][m] = a4.y;
        As[k4 + 2][m] = a4.z; As[k4 + 3][m] = a4.w;
    }
#pragma unroll
    for (int p = 0; p < 4; ++p) {   // stage B: 64 k x 64 cols
        int idx = t + p * 256;
        int kk = idx >> 4, c0 = (idx & 15) * 4;
        const float* wp = W + (size_t)(c0 >> 5) * 64 * 32
                            + (size_t)kk * 32 + (c0 & 31);
        *(float4*)&Bs[kk][c0] = *(const float4*)wp;
    }
    __syncthreads();
    float acc[4] = {};
#pragma unroll
    for (int k = 0; k < 64; ++k) {
        float a = As[k][ty];
        float4 b4 = *(const float4*)&Bs[k][tx * 4];
        acc[0] += a * b4.x; acc[1] += a * b4.y;
        acc[2] += a * b4.z; acc[3] += a * b4.w;
    }
    int col0 = tx * 4;
    int row = i0 + ty;
    float4 bi = *(const float4*)&bias[col0];
    float4 w1 = *(const float4*)&a1w[col0];
    float4 w2 = *(const float4*)&a2w[col0];
    float v0 = acc[0] + bi.x, v1 = acc[1] + bi.y;
    float v2 = acc[2] + bi.z, v3 = acc[3] + bi.w;
    float4 v4 = {v0, v1, v2, v3};
    *(float4*)&F[(size_t)row * 64 + col0] = v4;
    float p1 = v0 * w1.x + v1 * w1.y + v2 * w1.z + v3 * w1.w;
    float p2 = v0 * w2.x + v1 * w2.y + v2 * w2.z + v3 * w2.w;
#pragma unroll
    for (int off = 1; off < 8; off <<= 1) {
        p1 += __shfl_xor(p1, off);
        p2 += __shfl_xor(p2, off);
    }
    if ((tx & 7) == 0) {
        int head = tx >> 3;
        s1[head * GN + row] = p1 + a1b[head];
        s2i[row * 2 + head] = p2 + a2b[head];
    }
}

// ---------- shared attention body: edge list already in LDS -----------------
__device__ __forceinline__ void attn_body(
    int i, int t, int cnt, const int* colsS,
    float* w0, float* w1, float red[4][4], float part[4][64],
    const float* __restrict__ f, const float* __restrict__ s1,
    const float* __restrict__ s2i, float* __restrict__ xout, int ocol0)
{
    int wv = t >> 6, lane = t & 63;
    float s10 = s1[i], s11 = s1[GN + i];
    float m0 = -1e30f, m1 = -1e30f;
    for (int c = t; c < cnt; c += 256) {
        int j = colsS[c];
        float2 s2v = *(const float2*)&s2i[j * 2];
        float e0 = s10 + s2v.x; e0 = e0 > 0.f ? e0 : 0.01f * e0;
        float e1 = s11 + s2v.y; e1 = e1 > 0.f ? e1 : 0.01f * e1;
        w0[c] = e0; w1[c] = e1;
        m0 = fmaxf(m0, e0); m1 = fmaxf(m1, e1);
    }
#pragma unroll
    for (int off = 32; off; off >>= 1) {
        m0 = fmaxf(m0, __shfl_xor(m0, off));
        m1 = fmaxf(m1, __shfl_xor(m1, off));
    }
    if (lane == 0) { red[wv][0] = m0; red[wv][1] = m1; }
    __syncthreads();
    m0 = fmaxf(fmaxf(red[0][0], red[1][0]), fmaxf(red[2][0], red[3][0]));
    m1 = fmaxf(fmaxf(red[0][1], red[1][1]), fmaxf(red[2][1], red[3][1]));
    float sum0 = 0.f, sum1 = 0.f;
    for (int c = t; c < cnt; c += 256) {
        float v0 = __expf(w0[c] - m0); w0[c] = v0; sum0 += v0;
        float v1 = __expf(w1[c] - m1); w1[c] = v1; sum1 += v1;
    }
#pragma unroll
    for (int off = 32; off; off >>= 1) {
        sum0 += __shfl_xor(sum0, off);
        sum1 += __shfl_xor(sum1, off);
    }
    if (lane == 0) { red[wv][2] = sum0; red[wv][3] = sum1; }
    __syncthreads();
    sum0 = red[0][2] + red[1][2] + red[2][2] + red[3][2];
    sum1 = red[0][3] + red[1][3] + red[2][3] + red[3][3];
    int head = lane >> 5;
    float o = 0.f;
    for (int c = wv; c < cnt; c += 4) {
        int j = colsS[c];
        float wgt = head ? w1[c] : w0[c];
        o += wgt * f[(size_t)j * 64 + lane];
    }
    part[wv][lane] = o;
    __syncthreads();
    if (wv == 0) {
        o = part[0][lane] + part[1][lane] + part[2][lane] + part[3][lane];
        float denom = head ? sum1 : sum0;
        float v = o / denom;
        xout[(size_t)i * 192 + ocol0 + lane] = v > 0.f ? v : 0.f;
    }
}

// ---------- layer-1 attention with fused adj-row scan + CSR write -----------
// Scan compaction via __ballot: chain = cmp -> ballot -> popcll -> 1 atomic,
// no 6-step shfl_up prefix (R7 counters: scan is latency-chain-bound).
__global__ __launch_bounds__(256) void attn_csr_kernel(
    const float* __restrict__ adj, const float* __restrict__ f,
    const float* __restrict__ s1, const float* __restrict__ s2i,
    int* __restrict__ cnt_, int* __restrict__ col_,
    float* __restrict__ xout)
{
    __shared__ float w0[CAP], w1[CAP];
    __shared__ int colsS[CAP];
    __shared__ float red[4][4];
    __shared__ float part[4][64];
    __shared__ int lcnt;
    int i = blockIdx.x, t = threadIdx.x;
    int wv = t >> 6, lane = t & 63;
    if (t == 0) lcnt = 0;
    __syncthreads();
    const float* row = adj + (size_t)i * GN;
    int wbase = wv * 1024;
    unsigned long long below = (lane == 63) ? 0x7fffffffffffffffull
                                            : ((1ull << lane) - 1ull);
#pragma unroll
    for (int q = 0; q < 4; ++q) {
        int j = wbase + q * 256 + lane * 4;
        float4 v = *(const float4*)(row + j);
        unsigned long long m0 = __ballot(v.x != 0.f);
        unsigned long long m1 = __ballot(v.y != 0.f);
        unsigned long long m2 = __ballot(v.z != 0.f);
        unsigned long long m3 = __ballot(v.w != 0.f);
        int t0 = __popcll(m0), t1 = __popcll(m1), t2 = __popcll(m2), t3 = __popcll(m3);
        int total = t0 + t1 + t2 + t3;
        int basew = 0;
        if (lane == 0 && total) basew = atomicAdd(&lcnt, total);
        basew = __shfl(basew, 0);
        if (v.x != 0.f) { int p = basew + __popcll(m0 & below);
                          if (p < CAP) colsS[p] = j + 0; }
        if (v.y != 0.f) { int p = basew + t0 + __popcll(m1 & below);
                          if (p < CAP) colsS[p] = j + 1; }
        if (v.z != 0.f) { int p = basew + t0 + t1 + __popcll(m2 & below);
                          if (p < CAP) colsS[p] = j + 2; }
        if (v.w != 0.f) { int p = basew + t0 + t1 + t2 + __popcll(m3 & below);
                          if (p < CAP) colsS[p] = j + 3; }
    }
    __syncthreads();
    int cnt = lcnt < CAP ? lcnt : CAP;
    if (t == 0) cnt_[i] = cnt;
    int* gcols = col_ + (size_t)i * CAP;
    for (int c = t; c < cnt; c += 256) gcols[c] = colsS[c];
    attn_body(i, t, cnt, colsS, w0, w1, red, part, f, s1, s2i, xout, 0);
}

// ---------- layers 2/3 attention: edge list from global ---------------------
__global__ __launch_bounds__(256) void attn_kernel(
    const float* __restrict__ f, const float* __restrict__ s1,
    const float* __restrict__ s2i, const int* __restrict__ cnt_,
    const int* __restrict__ col_, float* __restrict__ xout, int ocol0)
{
    __shared__ float w0[CAP], w1[CAP];
    __shared__ int colsS[CAP];
    __shared__ float red[4][4];
    __shared__ float part[4][64];
    int i = blockIdx.x, t = threadIdx.x;
    int cnt = cnt_[i];
    const int* cols = col_ + (size_t)i * CAP;
    for (int c = t; c < cnt; c += 256) colsS[c] = cols[c];
    __syncthreads();
    attn_body(i, t, cnt, colsS, w0, w1, red, part, f, s1, s2i, xout, ocol0);
}

// ---------- fused pooling + classifier --------------------------------------
__global__ __launch_bounds__(192) void pool_classify(
    const float* __restrict__ hbuf, const int* __restrict__ batch,
    const float* __restrict__ Wf, const float* __restrict__ bfb,
    float* __restrict__ out)
{
    __shared__ int bnd[2];
    __shared__ float pooled[192];
    __shared__ float z[10];
    __shared__ float red[2];
    int g = blockIdx.x, t = threadIdx.x;
    if (t == 0) {
        int lo = 0, hi = GN;
        while (lo < hi) { int mid = (lo + hi) >> 1; if (batch[mid] < g) lo = mid + 1; else hi = mid; }
        bnd[0] = lo;
        hi = GN;
        while (lo < hi) { int mid = (lo + hi) >> 1; if (batch[mid] < g + 1) lo = mid + 1; else hi = mid; }
        bnd[1] = lo;
    }
    __syncthreads();
    int s = bnd[0], e = bnd[1];
    float a0 = 0.f, a1 = 0.f, a2 = 0.f, a3 = 0.f;
    int n = s;
    for (; n + 3 < e; n += 4) {
        a0 += hbuf[(size_t)(n + 0) * 192 + t];
        a1 += hbuf[(size_t)(n + 1) * 192 + t];
        a2 += hbuf[(size_t)(n + 2) * 192 + t];
        a3 += hbuf[(size_t)(n + 3) * 192 + t];
    }
    for (; n < e; ++n) a0 += hbuf[(size_t)n * 192 + t];
    float acc = (a0 + a1) + (a2 + a3);
    pooled[t] = (e > s) ? acc / (float)(e - s) : 0.f;
    __syncthreads();
    if (t < 10) {
        float zt = bfb[t];
        for (int c = 0; c < 192; ++c) zt += pooled[c] * Wf[c * 10 + t];
        z[t] = zt;
    }
    __syncthreads();
    if (t == 0) {
        float m = z[0];
        for (int o = 1; o < 10; ++o) m = fmaxf(m, z[o]);
        float ssum = 0.f;
        for (int o = 0; o < 10; ++o) ssum += __expf(z[o] - m);
        red[0] = m; red[1] = ssum;
    }
    __syncthreads();
    if (t < 10) out[g * 10 + t] = __expf(z[t] - red[0]) / red[1];
}

extern "C" void kernel_launch(void* const* d_in, const int* in_sizes, int n_in,
                              void* d_out, int out_size, void* d_ws, size_t ws_size,
                              hipStream_t stream)
{
    const float* x    = (const float*)d_in[0];
    const float* adj  = (const float*)d_in[1];
    const int*   batch= (const int*)d_in[2];
    const float* W1   = (const float*)d_in[3];
    const float* b1   = (const float*)d_in[4];
    const float* a1w1 = (const float*)d_in[5];
    const float* a1b1 = (const float*)d_in[6];
    const float* a2w1 = (const float*)d_in[7];
    const float* a2b1 = (const float*)d_in[8];
    const float* W2   = (const float*)d_in[9];
    const float* b2   = (const float*)d_in[10];
    const float* a1w2 = (const float*)d_in[11];
    const float* a1b2 = (const float*)d_in[12];
    const float* a2w2 = (const float*)d_in[13];
    const float* a2b2 = (const float*)d_in[14];
    const float* W3   = (const float*)d_in[15];
    const float* b3   = (const float*)d_in[16];
    const float* a1w3 = (const float*)d_in[17];
    const float* a1b3 = (const float*)d_in[18];
    const float* a2w3 = (const float*)d_in[19];
    const float* a2b3 = (const float*)d_in[20];
    const float* Wf   = (const float*)d_in[21];
    const float* bf   = (const float*)d_in[22];
    float* out = (float*)d_out;

    char* base = (char*)d_ws;
    int*   csr_cnt = (int*)(base + 0);            // 16 KiB
    float* s1      = (float*)(base + 16384);      // 32 KiB
    float* s2i     = (float*)(base + 49152);      // 32 KiB
    float* fbuf    = (float*)(base + 81920);      // 1 MiB
    float* hbuf    = (float*)(base + 1130496);    // 3 MiB
    float* pbuf    = (float*)(base + 4276224);    // 8 MiB (8 x 1 MiB partials)
    int*   csr_col = (int*)(base + 12664832);     // 8 MiB
    (void)ws_size; (void)n_in; (void)in_sizes; (void)out_size;

    linear_partial<512, 8><<<512, 256, 0, stream>>>(x, 512, W1, pbuf);
    reduce_scores<8><<<GN / 16, 256, 0, stream>>>(pbuf, b1, a1w1, a1b1, a2w1, a2b1,
                                                  fbuf, s1, s2i);
    attn_csr_kernel<<<GN, 256, 0, stream>>>(adj, fbuf, s1, s2i, csr_cnt, csr_col, hbuf);

    linear_scores16<<<GN / 16, 256, 0, stream>>>(hbuf, 192, W2, b2, a1w2, a1b2,
                                                 a2w2, a2b2, fbuf, s1, s2i);
    attn_kernel<<<GN, 256, 0, stream>>>(fbuf, s1, s2i, csr_cnt, csr_col, hbuf, 64);

    linear_scores16<<<GN / 16, 256, 0, stream>>>(hbuf + 64, 192, W3, b3, a1w3, a1b3,
                                                 a2w3, a2b3, fbuf, s1, s2i);
    attn_kernel<<<GN, 256, 0, stream>>>(fbuf, s1, s2i, csr_cnt, csr_col, hbuf, 128);

    pool_classify<<<NGRAPH, 192, 0, stream>>>(hbuf, batch, Wf, bf, out);
}